// Round 5
// baseline (2044.137 us; speedup 1.0000x reference)
//
#include <hip/hip_runtime.h>
#include <hip/hip_bf16.h>

typedef __bf16 bf16;
typedef bf16 bf16x8 __attribute__((ext_vector_type(8)));
typedef float f32x4 __attribute__((ext_vector_type(4)));

__device__ __forceinline__ void glds16(const void* g, void* l) {
    __builtin_amdgcn_global_load_lds(
        (const __attribute__((address_space(1))) void*)g,
        (__attribute__((address_space(3))) void*)l, 16, 0, 0);
}

__device__ __forceinline__ float sigm(float x) { return 1.0f / (1.0f + __expf(-x)); }
__device__ __forceinline__ float tanh_f(float x) { return 2.0f / (1.0f + __expf(-2.0f * x)) - 1.0f; }

// ---------------------------------------------------------------------------
// fp32 -> bf16 conversion of x + 11 matrices into one packed ws area.
// ---------------------------------------------------------------------------
struct Cvt11 { const float* src[11]; unsigned gcnt[11]; };  // gcnt = elems/8

__global__ __launch_bounds__(256) void cvt_all(Cvt11 a, bf16* __restrict__ dst,
                                               unsigned total_g) {
    unsigned g = blockIdx.x * 256 + threadIdx.x;
    if (g >= total_g) return;
    unsigned s = 0, base = 0;
    while (g >= base + a.gcnt[s]) { base += a.gcnt[s]; ++s; }
    const float* sp = a.src[s] + (size_t)(g - base) * 8;
    float4 v0 = ((const float4*)sp)[0];
    float4 v1 = ((const float4*)sp)[1];
    bf16x8 o;
    o[0] = (bf16)v0.x; o[1] = (bf16)v0.y; o[2] = (bf16)v0.z; o[3] = (bf16)v0.w;
    o[4] = (bf16)v1.x; o[5] = (bf16)v1.y; o[6] = (bf16)v1.z; o[7] = (bf16)v1.w;
    *(bf16x8*)(dst + (size_t)g * 8) = o;
}

// Pack WcP[oct=68][2048][8]: oct o holds cols o*8..o*8+7 of
// Wcomb[2048,544] = Whh[2048,512] || Wih[2048,16] || zeros[16], bf16.
__global__ __launch_bounds__(128) void pack_w(const float* __restrict__ Whh,
                                              const float* __restrict__ Wih,
                                              bf16* __restrict__ WcP) {
    int row = blockIdx.x, seg = threadIdx.x;
    if (seg >= 68) return;
    bf16x8 o = {};
    if (seg < 64) {
        const float* sp = Whh + (size_t)row * 512 + seg * 8;
        float4 v0 = ((const float4*)sp)[0];
        float4 v1 = ((const float4*)sp)[1];
        o[0]=(bf16)v0.x; o[1]=(bf16)v0.y; o[2]=(bf16)v0.z; o[3]=(bf16)v0.w;
        o[4]=(bf16)v1.x; o[5]=(bf16)v1.y; o[6]=(bf16)v1.z; o[7]=(bf16)v1.w;
    } else if (seg < 66) {
        const float* sp = Wih + (size_t)row * 16 + (seg - 64) * 8;
        float4 v0 = ((const float4*)sp)[0];
        float4 v1 = ((const float4*)sp)[1];
        o[0]=(bf16)v0.x; o[1]=(bf16)v0.y; o[2]=(bf16)v0.z; o[3]=(bf16)v0.w;
        o[4]=(bf16)v1.x; o[5]=(bf16)v1.y; o[6]=(bf16)v1.z; o[7]=(bf16)v1.w;
    }
    *(bf16x8*)(WcP + ((size_t)seg * 2048 + row) * 8) = o;
}

// Zero pad cols 528..543 of both h buffers + zero all barrier/claim words.
// bvars layout (uints): [0..7] per-XCD claim counters | [8..9] grid rec |
// [16 + mb*16 ..] 32 group records {cnt,gen}.
__global__ __launch_bounds__(256) void zero_pad(bf16* __restrict__ h0,
                                                bf16* __restrict__ h1,
                                                unsigned* __restrict__ bvars) {
    int g = blockIdx.x * 256 + threadIdx.x;  // 4096*2*2 = 16384
    if (g < 132) ((uint4*)bvars)[g] = (uint4){0u, 0u, 0u, 0u};
    int row = g >> 2, b = (g >> 1) & 1, half = g & 1;
    bf16* p = (b ? h1 : h0) + (size_t)row * 544 + 528 + half * 8;
    *(bf16x8*)p = (bf16x8){};
}

// ---------------------------------------------------------------------------
// GEMM: C[M,N](ldc) = act(A[M,K] @ W[N,K]^T + bias).  (prologue only)
// ---------------------------------------------------------------------------
template <int ACT, typename OutT>
__global__ __launch_bounds__(256) void gemm_bt(
    const bf16* __restrict__ A, const bf16* __restrict__ W,
    const float* __restrict__ bias, OutT* __restrict__ C,
    int M, int N, int K, int ldc)
{
    __shared__ __attribute__((aligned(16))) bf16 sA[64 * 32];   // 4 KB
    __shared__ __attribute__((aligned(16))) bf16 sB[128 * 32];  // 8 KB
    const int t = threadIdx.x;
    const int lane = t & 63, w = t >> 6;
    const int wm = w >> 1, wn = w & 1;
    const int quad = lane >> 4, l16 = lane & 15;
    const int m0 = blockIdx.y * 64, n0 = blockIdx.x * 128;

    f32x4 acc[2][4] = {};

    const int nk = K >> 5;
    for (int kc = 0; kc < nk; ++kc) {
        const int k0 = kc << 5;
        if (kc) __syncthreads();
        {
            int row = t >> 2, kof = (t & 3) << 3;
            glds16(A + (size_t)(m0 + row) * K + k0 + kof, (char*)sA + (w << 10));
        }
        for (int i = 0; i < 2; ++i) {
            int gi = (i << 8) + t;
            int row = gi >> 2, kof = (gi & 3) << 3;
            glds16(W + (size_t)(n0 + row) * K + k0 + kof,
                   (char*)sB + (i << 12) + (w << 10));
        }
        __syncthreads();
        bf16x8 af[2], bfr[4];
        for (int mi = 0; mi < 2; ++mi)
            af[mi] = *(const bf16x8*)(sA + ((wm * 32 + mi * 16 + l16) * 32 + quad * 8));
        for (int ni = 0; ni < 4; ++ni)
            bfr[ni] = *(const bf16x8*)(sB + ((wn * 64 + ni * 16 + l16) * 32 + quad * 8));
        for (int mi = 0; mi < 2; ++mi)
            for (int ni = 0; ni < 4; ++ni)
                acc[mi][ni] = __builtin_amdgcn_mfma_f32_16x16x32_bf16(
                    af[mi], bfr[ni], acc[mi][ni], 0, 0, 0);
    }
    for (int mi = 0; mi < 2; ++mi) {
        for (int ni = 0; ni < 4; ++ni) {
            int gn = n0 + wn * 64 + ni * 16 + l16;
            float bv = bias[gn];
            for (int r = 0; r < 4; ++r) {
                int gm = m0 + wm * 32 + mi * 16 + quad * 4 + r;
                float v = acc[mi][ni][r] + bv;
                if (ACT) v = v >= 0.f ? v : 0.2f * v;
                C[(size_t)gm * ldc + gn] = (OutT)v;
            }
        }
    }
}

// ---------------------------------------------------------------------------
// MFMA head (used once, for x0): writes softmax/sigmoid into h0b cols 512..527.
// ---------------------------------------------------------------------------
__global__ __launch_bounds__(256) void head_mfma(
    const bf16* __restrict__ A, int lda,
    const bf16* __restrict__ Wp16,
    const float* __restrict__ bias,
    bf16* __restrict__ xt_dst, int ldx)
{
    const int t = threadIdx.x;
    const int lane = t & 63, w = t >> 6;
    const int quad = lane >> 4, l16 = lane & 15;
    const int r0 = blockIdx.x * 64 + w * 16;
    f32x4 acc = {};
    for (int kk = 0; kk < 16; ++kk) {
        bf16x8 a = *(const bf16x8*)(A + (size_t)(r0 + l16) * lda + kk * 32 + quad * 8);
        bf16x8 b = *(const bf16x8*)(Wp16 + (size_t)l16 * 512 + kk * 32 + quad * 8);
        acc = __builtin_amdgcn_mfma_f32_16x16x32_bf16(a, b, acc, 0, 0, 0);
    }
    const int n = l16;
    const float bv = bias[n];
    for (int r = 0; r < 4; ++r) {
        float p = acc[r] + bv;
        float vmax = (n == 15) ? -3.0e38f : p;
        for (int m = 1; m < 16; m <<= 1) vmax = fmaxf(vmax, __shfl_xor(vmax, m));
        float e = (n == 15) ? 0.f : __expf(p - vmax);
        float s = e;
        for (int m = 1; m < 16; m <<= 1) s += __shfl_xor(s, m);
        float res = (n == 15) ? sigm(p) : e / s;
        int gr = r0 + quad * 4 + r;
        xt_dst[(size_t)gr * ldx + n] = (bf16)res;
    }
}

// ---------------------------------------------------------------------------
// Group barrier.  light (group verified same-XCD): __syncthreads drains each
// wave's stores to the shared per-XCD L2 (vector L1 is write-through), 16
// device-scope atomics arbitrate, buffer_inv (plain = L1-only on gfx94x
// lowering) drops stale L1 lines.  heavy (cross-XCD fallback): __threadfence.
// ---------------------------------------------------------------------------
__device__ __forceinline__ void grp_barrier(unsigned* rec, unsigned nblk,
                                            bool light) {
    __syncthreads();
    if (threadIdx.x == 0) {
        if (!light) __threadfence();
        unsigned g = __hip_atomic_load(rec + 1, __ATOMIC_RELAXED,
                                       __HIP_MEMORY_SCOPE_AGENT);
        unsigned a = __hip_atomic_fetch_add(rec, 1u, __ATOMIC_RELAXED,
                                            __HIP_MEMORY_SCOPE_AGENT);
        if (a == nblk - 1u) {
            __hip_atomic_store(rec, 0u, __ATOMIC_RELAXED,
                               __HIP_MEMORY_SCOPE_AGENT);
            __hip_atomic_store(rec + 1, g + 1u, __ATOMIC_RELAXED,
                               __HIP_MEMORY_SCOPE_AGENT);
        } else {
            while (__hip_atomic_load(rec + 1, __ATOMIC_RELAXED,
                                     __HIP_MEMORY_SCOPE_AGENT) == g)
                __builtin_amdgcn_s_sleep(2);
        }
        if (!light) __threadfence();
    }
    __syncthreads();
    asm volatile("buffer_inv" ::: "memory");  // L1 invalidate
}

// ---------------------------------------------------------------------------
// Persistent fused LSTM, XCD-claimed work assignment.
// Each block reads its real XCC_ID and claims slot s from cnt[xcd]:
//   mb = xcd*4 + s/16, jb = s%16  -> every 16-block mb-group provably
// one-XCD (512 blocks at 2/CU = exactly 64/XCD; LDS pad forces 2/CU).
// Credibility (all cnt[k]==64) checked after a one-time grid arrival
// barrier; else fall back to bid-based work + heavy barriers (= R4).
// Groups are fully independent -> free-run with 1 light barrier/step.
// c resident in LDS; GEMM = direct-fragment register-dbuf engine.
// ---------------------------------------------------------------------------
__global__ __launch_bounds__(256, 2) void lstm_persist(
    bf16* __restrict__ hb0, bf16* __restrict__ hb1,     // [4096,544]
    const bf16* __restrict__ WcP,   // [68][2048][8] oct-packed
    const bf16* __restrict__ Wp16,  // [16,512]
    const float* __restrict__ bih, const float* __restrict__ bhh,
    const float* __restrict__ bp,
    const float* __restrict__ cb,   // [4096,512] fp32 (c0, read once)
    float* __restrict__ P0, float* __restrict__ P1,  // ppart dbl buffers
    float* __restrict__ outp,       // [4096, 512] = [B, T*16]
    unsigned* __restrict__ bvars)
{
    __shared__ __attribute__((aligned(16))) bf16 xA[128 * 32];  // 8 KB
    __shared__ __attribute__((aligned(16))) bf16 sH[128 * 32];  // 8 KB
    __shared__ float sC[128 * 32];                              // 16 KB
    __shared__ unsigned s_mb, s_jb, s_light;
    __shared__ char pad_[24576];    // occupancy cap: 57 KB -> 2 blocks/CU max
    const int t = threadIdx.x;
    const int lane = t & 63, w = t >> 6;
    const int wm = w >> 1, wn = w & 1;
    const int quad = lane >> 4, l16 = lane & 15;

    unsigned* cnt  = bvars;        // [8] per-XCD claim counters
    unsigned* Grec = bvars + 8;    // grid arrival {cnt,gen}
    unsigned* grecs = bvars + 16;  // 32 group records, 16 uints apart

    // ---- claim + one-time grid arrival + credibility ----
    if (t == 0) {
        unsigned xcc;
        asm volatile("s_getreg_b32 %0, hwreg(HW_REG_XCC_ID, 0, 4)" : "=s"(xcc));
        xcc &= 7u;
        unsigned slot = __hip_atomic_fetch_add(cnt + xcc, 1u, __ATOMIC_RELAXED,
                                               __HIP_MEMORY_SCOPE_AGENT);
        // grid arrival barrier (atomics only; claim data travels via atomics)
        unsigned g = __hip_atomic_load(Grec + 1, __ATOMIC_RELAXED,
                                       __HIP_MEMORY_SCOPE_AGENT);
        unsigned a = __hip_atomic_fetch_add(Grec, 1u, __ATOMIC_RELAXED,
                                            __HIP_MEMORY_SCOPE_AGENT);
        if (a == 511u) {
            __hip_atomic_store(Grec, 0u, __ATOMIC_RELAXED,
                               __HIP_MEMORY_SCOPE_AGENT);
            __hip_atomic_store(Grec + 1, g + 1u, __ATOMIC_RELAXED,
                               __HIP_MEMORY_SCOPE_AGENT);
        } else {
            while (__hip_atomic_load(Grec + 1, __ATOMIC_RELAXED,
                                     __HIP_MEMORY_SCOPE_AGENT) == g)
                __builtin_amdgcn_s_sleep(16);
        }
        bool ok = (slot < 64u);
        for (int k = 0; k < 8; ++k)
            ok &= (__hip_atomic_load(cnt + k, __ATOMIC_RELAXED,
                                     __HIP_MEMORY_SCOPE_AGENT) == 64u);
        if (ok) { s_mb = xcc * 4u + (slot >> 4); s_jb = slot & 15u; s_light = 1u; }
        else    { s_mb = blockIdx.x & 31u; s_jb = blockIdx.x >> 5; s_light = 0u; }
        pad_[0] = (char)slot;  // keep pad_ live (occupancy cap)
    }
    __syncthreads();
    asm volatile("" :: "v"((int)pad_[0]));  // anchor pad_ against DCE
    const int mb = (int)s_mb, jb = (int)s_jb;
    const bool light = (s_light != 0u);
    const int m0 = mb * 128, j0 = jb * 32;
    const int j = j0 + wn * 16 + l16;
    unsigned* grec = grecs + mb * 16;

    // init: c slice -> LDS (resident all 32 steps), biases, Wp fragment
    for (int mi = 0; mi < 4; ++mi)
        for (int r = 0; r < 4; ++r) {
            int lr = wm * 64 + mi * 16 + quad * 4 + r;
            sC[lr * 32 + wn * 16 + l16] = cb[(size_t)(m0 + lr) * 512 + j];
        }
    float bsum[4];
#pragma unroll
    for (int g2 = 0; g2 < 4; ++g2)
        bsum[g2] = bih[(g2 << 9) + j] + bhh[(g2 << 9) + j];
    const bf16x8 wpf = *(const bf16x8*)(Wp16 + (size_t)l16 * 512 + j0 + quad * 8);

    unsigned aoffs[4];
#pragma unroll
    for (int mi = 0; mi < 4; ++mi)
        aoffs[mi] = (unsigned)((m0 + wm * 64 + mi * 16 + l16) * 544 + quad * 8);
    const bf16* brow[4];
#pragma unroll
    for (int g2 = 0; g2 < 4; ++g2)
        brow[g2] = WcP + ((size_t)(g2 * 512 + j0 + wn * 16 + l16)) * 8
                       + (size_t)quad * (2048 * 8);

#pragma unroll 1
    for (int st = 0; st < 32; ++st) {
        const bf16* hinp = (st & 1) ? hb1 : hb0;
        bf16* houtp = (st & 1) ? hb0 : hb1;
        const float* ppin = (st & 1) ? P1 : P0;
        float* ppout = (st & 1) ? P0 : P1;

        bf16x8 afb[2][4], bfb[2][4];
        auto loadG = [&](int kk, int buf) {
#pragma unroll
            for (int mi = 0; mi < 4; ++mi)
                afb[buf][mi] = *(const bf16x8*)(hinp + aoffs[mi] + kk * 32);
#pragma unroll
            for (int g2 = 0; g2 < 4; ++g2)
                bfb[buf][g2] = *(const bf16x8*)(brow[g2] + (size_t)kk * (4 * 2048 * 8));
        };
        loadG(0, 0);  // chunk-0 loads in flight while prologue runs

        if (st == 0) {
            // xt tile from hin cols 512..543 (head_mfma + zero_pad output)
            for (int i = 0; i < 2; ++i) {
                int g = (i << 8) + t, row = g >> 2, seg = g & 3;
                *(bf16x8*)(xA + row * 32 + seg * 8) =
                    *(const bf16x8*)(hinp + (size_t)(m0 + row) * 544 + 512 + seg * 8);
            }
        } else if (t < 128) {
            // reduce 16 partials -> softmax head -> xA (+ write ys[st-1])
            const int row = m0 + t;
            float p[16];
#pragma unroll
            for (int n = 0; n < 16; ++n) p[n] = bp[n];
            for (int q = 0; q < 16; ++q) {
                const float4* pp = (const float4*)(ppin + ((size_t)(q << 12) + row) * 16);
                float4 v0 = pp[0], v1 = pp[1], v2 = pp[2], v3 = pp[3];
                p[0]+=v0.x; p[1]+=v0.y; p[2]+=v0.z; p[3]+=v0.w;
                p[4]+=v1.x; p[5]+=v1.y; p[6]+=v1.z; p[7]+=v1.w;
                p[8]+=v2.x; p[9]+=v2.y; p[10]+=v2.z; p[11]+=v2.w;
                p[12]+=v3.x; p[13]+=v3.y; p[14]+=v3.z; p[15]+=v3.w;
            }
            float vmax = p[0];
#pragma unroll
            for (int n = 1; n < 15; ++n) vmax = fmaxf(vmax, p[n]);
            float e[15], s = 0.f;
#pragma unroll
            for (int n = 0; n < 15; ++n) { e[n] = __expf(p[n] - vmax); s += e[n]; }
            float inv = 1.0f / s;
            float lastv = sigm(p[15]);
            bf16* xr = xA + t * 32;
#pragma unroll
            for (int n = 0; n < 15; ++n) xr[n] = (bf16)(e[n] * inv);
            xr[15] = (bf16)lastv;
            *(bf16x8*)(xr + 16) = (bf16x8){};
            *(bf16x8*)(xr + 24) = (bf16x8){};
            if (jb == 0) {
                float* op = outp + (size_t)row * 512 + (st - 1) * 16;
#pragma unroll
                for (int n = 0; n < 15; ++n) op[n] = e[n] * inv;
                op[15] = lastv;
            }
        }
        __syncthreads();  // xA ready

        f32x4 acc[4][4] = {};  // [mi][gate]
#pragma unroll
        for (int kk = 0; kk < 17; ++kk) {
            const int cur = kk & 1, nxt = cur ^ 1;
            if (kk < 15) {
                loadG(kk + 1, nxt);
            } else if (kk == 15) {  // chunk 16: xt from xA
#pragma unroll
                for (int mi = 0; mi < 4; ++mi)
                    afb[nxt][mi] = *(const bf16x8*)(
                        xA + (wm * 64 + mi * 16 + l16) * 32 + quad * 8);
#pragma unroll
                for (int g2 = 0; g2 < 4; ++g2)
                    bfb[nxt][g2] = *(const bf16x8*)(brow[g2] + (size_t)16 * (4 * 2048 * 8));
            }
#pragma unroll
            for (int mi = 0; mi < 4; ++mi)
#pragma unroll
                for (int g2 = 0; g2 < 4; ++g2)
                    acc[mi][g2] = __builtin_amdgcn_mfma_f32_16x16x32_bf16(
                        afb[cur][mi], bfb[cur][g2], acc[mi][g2], 0, 0, 0);
        }

        // epilogue: gates, c update (LDS, thread-private), h + sH write
#pragma unroll
        for (int mi = 0; mi < 4; ++mi) {
#pragma unroll
            for (int r = 0; r < 4; ++r) {
                int lr = wm * 64 + mi * 16 + quad * 4 + r;
                int gm = m0 + lr;
                float i_ = sigm(acc[mi][0][r] + bsum[0]);
                float f_ = sigm(acc[mi][1][r] + bsum[1]);
                float g_ = tanh_f(acc[mi][2][r] + bsum[2]);
                float o_ = sigm(acc[mi][3][r] + bsum[3]);
                int ci = lr * 32 + wn * 16 + l16;
                float cn = f_ * sC[ci] + i_ * g_;
                sC[ci] = cn;
                float hv = o_ * tanh_f(cn);
                bf16 hb = (bf16)hv;
                if (st != 31) houtp[(size_t)gm * 544 + j] = hb;
                sH[ci] = hb;
            }
        }
        __syncthreads();

        // head partial: ppout[jb][rows][16] = h_tile @ Wp[:, j0:j0+32]^T
        {
            const int r0h = w * 32;
            bf16x8 a0 = *(const bf16x8*)(sH + (r0h + l16) * 32 + quad * 8);
            bf16x8 a1 = *(const bf16x8*)(sH + (r0h + 16 + l16) * 32 + quad * 8);
            f32x4 p0 = {}, p1 = {};
            p0 = __builtin_amdgcn_mfma_f32_16x16x32_bf16(a0, wpf, p0, 0, 0, 0);
            p1 = __builtin_amdgcn_mfma_f32_16x16x32_bf16(a1, wpf, p1, 0, 0, 0);
#pragma unroll
            for (int r = 0; r < 4; ++r) {
                int row0 = m0 + r0h + quad * 4 + r;
                ppout[((size_t)jb * 4096 + row0) * 16 + l16] = p0[r];
                ppout[((size_t)jb * 4096 + row0 + 16) * 16 + l16] = p1[r];
            }
        }

        grp_barrier(grec, 16u, light);  // group-only: h/ppart exchange
    }

    // final: ys[31] from P0 (step 31 wrote ppout = P0)
    if (jb == 0 && t < 128) {
        const int row = m0 + t;
        float p[16];
#pragma unroll
        for (int n = 0; n < 16; ++n) p[n] = bp[n];
        for (int q = 0; q < 16; ++q) {
            const float4* pp = (const float4*)(P0 + ((size_t)(q << 12) + row) * 16);
            float4 v0 = pp[0], v1 = pp[1], v2 = pp[2], v3 = pp[3];
            p[0]+=v0.x; p[1]+=v0.y; p[2]+=v0.z; p[3]+=v0.w;
            p[4]+=v1.x; p[5]+=v1.y; p[6]+=v1.z; p[7]+=v1.w;
            p[8]+=v2.x; p[9]+=v2.y; p[10]+=v2.z; p[11]+=v2.w;
            p[12]+=v3.x; p[13]+=v3.y; p[14]+=v3.z; p[15]+=v3.w;
        }
        float vmax = p[0];
#pragma unroll
        for (int n = 1; n < 15; ++n) vmax = fmaxf(vmax, p[n]);
        float e[15], s = 0.f;
#pragma unroll
        for (int n = 0; n < 15; ++n) { e[n] = __expf(p[n] - vmax); s += e[n]; }
        float inv = 1.0f / s;
        float* op = outp + (size_t)row * 512 + 31 * 16;
#pragma unroll
        for (int n = 0; n < 15; ++n) op[n] = e[n] * inv;
        op[15] = sigm(p[15]);
    }
}

// ---------------------------------------------------------------------------
extern "C" void kernel_launch(void* const* d_in, const int* in_sizes, int n_in,
                              void* d_out, int out_size, void* d_ws, size_t ws_size,
                              hipStream_t stream) {
    const float* xf   = (const float*)d_in[0];
    const float* W1f  = (const float*)d_in[1];  const float* b1  = (const float*)d_in[2];
    const float* W2f  = (const float*)d_in[3];  const float* b2  = (const float*)d_in[4];
    const float* W3f  = (const float*)d_in[5];  const float* b3  = (const float*)d_in[6];
    const float* Wh1f = (const float*)d_in[7];  const float* bh1 = (const float*)d_in[8];
    const float* Wh2f = (const float*)d_in[9];  const float* bh2 = (const float*)d_in[10];
    const float* Wc1f = (const float*)d_in[11]; const float* bc1 = (const float*)d_in[12];
    const float* Wc2f = (const float*)d_in[13]; const float* bc2 = (const float*)d_in[14];
    const float* Wx1f = (const float*)d_in[15]; const float* bx1 = (const float*)d_in[16];
    const float* Wx2f = (const float*)d_in[17]; const float* bx2 = (const float*)d_in[18];
    const float* Wihf = (const float*)d_in[19]; const float* bih = (const float*)d_in[20];
    const float* Whhf = (const float*)d_in[21]; const float* bhh = (const float*)d_in[22];
    const float* Wpf  = (const float*)d_in[23]; const float* bp  = (const float*)d_in[24];
    float* out = (float*)d_out;
    char* ws = (char*)d_ws;

    // layout (bytes): h1b/bufA 0..4456448 | bufB ..8650752 | h0b ..13107200 |
    // cb ..21495808 | WcP ..23724032 | cvt ..28606464 | bvars ..28608576
    bf16*  h1b  = (bf16*)(ws + 0);            // [4096,544]; early: z-buf (ldc 512)
    bf16*  bufA = h1b;                        //   alias — z3 dead before step 0
    bf16*  bufB = (bf16*)(ws + 4456448);      // [4096,512]; loop: ppart P0
    bf16*  h0b  = (bf16*)(ws + 8650752);      // [4096,544]
    float* cb   = (float*)(ws + 13107200);    // [4096,512] fp32
    bf16*  WcP  = (bf16*)(ws + 21495808);     // [68][2048][8] = 2228224 B
    bf16*  cvt  = (bf16*)(ws + 23724032);     // packed bf16 weights
    unsigned* bvars = (unsigned*)(ws + 28606464);  // uint4[132] = 2112 B

    const unsigned Ns[11] = {
        4096u * 128u,  // x
        512u * 128u,   // W1
        512u * 512u, 512u * 512u, 512u * 512u, 512u * 512u,  // W2,W3,Wh1,Wh2
        512u * 512u, 512u * 512u, 512u * 512u,               // Wc1,Wc2,Wx1
        16u * 512u,    // Wx2
        16u * 512u     // Wp
    };
    const float* srcs[11] = { xf, W1f, W2f, W3f, Wh1f, Wh2f, Wc1f, Wc2f,
                              Wx1f, Wx2f, Wpf };
    Cvt11 ca;
    unsigned off[12]; off[0] = 0;
    for (int i = 0; i < 11; ++i) {
        ca.src[i] = srcs[i];
        ca.gcnt[i] = Ns[i] >> 3;
        off[i + 1] = off[i] + Ns[i];
    }
    unsigned total_g = off[11] >> 3;
    cvt_all<<<dim3((total_g + 255) / 256), dim3(256), 0, stream>>>(ca, cvt, total_g);
    pack_w<<<dim3(2048), dim3(128), 0, stream>>>(Whhf, Wihf, WcP);

    const bf16* xb   = cvt + off[0];
    const bf16* W1b  = cvt + off[1];
    const bf16* W2b  = cvt + off[2];
    const bf16* W3b  = cvt + off[3];
    const bf16* Wh1b = cvt + off[4];
    const bf16* Wh2b = cvt + off[5];
    const bf16* Wc1b = cvt + off[6];
    const bf16* Wc2b = cvt + off[7];
    const bf16* Wx1b = cvt + off[8];
    const bf16* Wx2b = cvt + off[9];
    const bf16* Wpb  = cvt + off[10];

    // ppart double buffers: P0 = bufB (dead after head_mfma), P1 = first 4 MB
    // of cvt area (dead after prologue GEMMs; Wx2b/Wpb live past 4.6 MB).
    float* P0 = (float*)bufB;
    float* P1 = (float*)cvt;

    dim3 blk(256);
    dim3 gg(4, 64);  // N/128 x M/64
    gemm_bt<1, bf16 ><<<gg, blk, 0, stream>>>(xb,   W1b,  b1,  bufA, 4096, 512, 128, 512);
    gemm_bt<1, bf16 ><<<gg, blk, 0, stream>>>(bufA, W2b,  b2,  bufB, 4096, 512, 512, 512);
    gemm_bt<1, bf16 ><<<gg, blk, 0, stream>>>(bufB, W3b,  b3,  bufA, 4096, 512, 512, 512);
    gemm_bt<1, bf16 ><<<gg, blk, 0, stream>>>(bufA, Wh1b, bh1, bufB, 4096, 512, 512, 512);
    gemm_bt<0, bf16 ><<<gg, blk, 0, stream>>>(bufB, Wh2b, bh2, h0b,  4096, 512, 512, 544);
    gemm_bt<1, bf16 ><<<gg, blk, 0, stream>>>(bufA, Wc1b, bc1, bufB, 4096, 512, 512, 512);
    gemm_bt<0, float><<<gg, blk, 0, stream>>>(bufB, Wc2b, bc2, cb,   4096, 512, 512, 512);
    gemm_bt<1, bf16 ><<<gg, blk, 0, stream>>>(bufA, Wx1b, bx1, bufB, 4096, 512, 512, 512);
    // bufA (=h1b) dead from here; zero pads + barrier init before the loop
    zero_pad<<<dim3(64), blk, 0, stream>>>(h0b, h1b, bvars);
    head_mfma<<<dim3(64), blk, 0, stream>>>(bufB, 512, Wx2b, bx2, h0b + 512, 544);

    // one persistent kernel replaces all 32 step launches + head_final
    lstm_persist<<<dim3(512), blk, 0, stream>>>(h0b, h1b, WcP, Wpb,
                                                bih, bhh, bp, cb,
                                                P0, P1, out, bvars);
}

// Round 6
// 1570.124 us; speedup vs baseline: 1.3019x; 1.3019x over previous
//
#include <hip/hip_runtime.h>
#include <hip/hip_bf16.h>

typedef __bf16 bf16;
typedef bf16 bf16x8 __attribute__((ext_vector_type(8)));
typedef float f32x4 __attribute__((ext_vector_type(4)));

__device__ __forceinline__ void glds16(const void* g, void* l) {       // cached
    __builtin_amdgcn_global_load_lds(
        (const __attribute__((address_space(1))) void*)g,
        (__attribute__((address_space(3))) void*)l, 16, 0, 0);
}
__device__ __forceinline__ void glds16_byp(const void* g, void* l) {   // sc0|sc1
    __builtin_amdgcn_global_load_lds(
        (const __attribute__((address_space(1))) void*)g,
        (__attribute__((address_space(3))) void*)l, 16, 0, 17);
}

__device__ __forceinline__ float sigm(float x) { return 1.0f / (1.0f + __expf(-x)); }
__device__ __forceinline__ float tanh_f(float x) { return 2.0f / (1.0f + __expf(-2.0f * x)) - 1.0f; }

// ---------------------------------------------------------------------------
// fp32 -> bf16 conversion of x + 11 matrices into one packed ws area.
// ---------------------------------------------------------------------------
struct Cvt11 { const float* src[11]; unsigned gcnt[11]; };  // gcnt = elems/8

__global__ __launch_bounds__(256) void cvt_all(Cvt11 a, bf16* __restrict__ dst,
                                               unsigned total_g) {
    unsigned g = blockIdx.x * 256 + threadIdx.x;
    if (g >= total_g) return;
    unsigned s = 0, base = 0;
    while (g >= base + a.gcnt[s]) { base += a.gcnt[s]; ++s; }
    const float* sp = a.src[s] + (size_t)(g - base) * 8;
    float4 v0 = ((const float4*)sp)[0];
    float4 v1 = ((const float4*)sp)[1];
    bf16x8 o;
    o[0] = (bf16)v0.x; o[1] = (bf16)v0.y; o[2] = (bf16)v0.z; o[3] = (bf16)v0.w;
    o[4] = (bf16)v1.x; o[5] = (bf16)v1.y; o[6] = (bf16)v1.z; o[7] = (bf16)v1.w;
    *(bf16x8*)(dst + (size_t)g * 8) = o;
}

// Pack Wcomb[2048,544] = Whh[2048,512] || Wih[2048,16] || zeros[16], bf16.
__global__ __launch_bounds__(128) void pack_w(const float* __restrict__ Whh,
                                              const float* __restrict__ Wih,
                                              bf16* __restrict__ Wc) {
    int row = blockIdx.x, seg = threadIdx.x;
    if (seg >= 68) return;
    bf16x8 o = {};
    if (seg < 64) {
        const float* sp = Whh + (size_t)row * 512 + seg * 8;
        float4 v0 = ((const float4*)sp)[0];
        float4 v1 = ((const float4*)sp)[1];
        o[0]=(bf16)v0.x; o[1]=(bf16)v0.y; o[2]=(bf16)v0.z; o[3]=(bf16)v0.w;
        o[4]=(bf16)v1.x; o[5]=(bf16)v1.y; o[6]=(bf16)v1.z; o[7]=(bf16)v1.w;
    } else if (seg < 66) {
        const float* sp = Wih + (size_t)row * 16 + (seg - 64) * 8;
        float4 v0 = ((const float4*)sp)[0];
        float4 v1 = ((const float4*)sp)[1];
        o[0]=(bf16)v0.x; o[1]=(bf16)v0.y; o[2]=(bf16)v0.z; o[3]=(bf16)v0.w;
        o[4]=(bf16)v1.x; o[5]=(bf16)v1.y; o[6]=(bf16)v1.z; o[7]=(bf16)v1.w;
    }
    *(bf16x8*)(Wc + (size_t)row * 544 + seg * 8) = o;
}

__global__ __launch_bounds__(256) void init_bvars(unsigned* __restrict__ bvars) {
    int t = threadIdx.x;              // 512 uints of group records
    bvars[t] = 0u; bvars[t + 256] = 0u;
}

// ---------------------------------------------------------------------------
// GEMM: C[M,N](ldc) = act(A[M,K] @ W[N,K]^T + bias).  (prologue, verified)
// ---------------------------------------------------------------------------
template <int ACT, typename OutT>
__global__ __launch_bounds__(256) void gemm_bt(
    const bf16* __restrict__ A, const bf16* __restrict__ W,
    const float* __restrict__ bias, OutT* __restrict__ C,
    int M, int N, int K, int ldc)
{
    __shared__ __attribute__((aligned(16))) bf16 sA[64 * 32];
    __shared__ __attribute__((aligned(16))) bf16 sB[128 * 32];
    const int t = threadIdx.x;
    const int lane = t & 63, w = t >> 6;
    const int wm = w >> 1, wn = w & 1;
    const int quad = lane >> 4, l16 = lane & 15;
    const int m0 = blockIdx.y * 64, n0 = blockIdx.x * 128;

    f32x4 acc[2][4] = {};
    const int nk = K >> 5;
    for (int kc = 0; kc < nk; ++kc) {
        const int k0 = kc << 5;
        if (kc) __syncthreads();
        {
            int row = t >> 2, kof = (t & 3) << 3;
            glds16(A + (size_t)(m0 + row) * K + k0 + kof, (char*)sA + (w << 10));
        }
        for (int i = 0; i < 2; ++i) {
            int gi = (i << 8) + t;
            int row = gi >> 2, kof = (gi & 3) << 3;
            glds16(W + (size_t)(n0 + row) * K + k0 + kof,
                   (char*)sB + (i << 12) + (w << 10));
        }
        __syncthreads();
        bf16x8 af[2], bfr[4];
        for (int mi = 0; mi < 2; ++mi)
            af[mi] = *(const bf16x8*)(sA + ((wm * 32 + mi * 16 + l16) * 32 + quad * 8));
        for (int ni = 0; ni < 4; ++ni)
            bfr[ni] = *(const bf16x8*)(sB + ((wn * 64 + ni * 16 + l16) * 32 + quad * 8));
        for (int mi = 0; mi < 2; ++mi)
            for (int ni = 0; ni < 4; ++ni)
                acc[mi][ni] = __builtin_amdgcn_mfma_f32_16x16x32_bf16(
                    af[mi], bfr[ni], acc[mi][ni], 0, 0, 0);
    }
    for (int mi = 0; mi < 2; ++mi) {
        for (int ni = 0; ni < 4; ++ni) {
            int gn = n0 + wn * 64 + ni * 16 + l16;
            float bv = bias[gn];
            for (int r = 0; r < 4; ++r) {
                int gm = m0 + wm * 32 + mi * 16 + quad * 4 + r;
                float v = acc[mi][ni][r] + bv;
                if (ACT) v = v >= 0.f ? v : 0.2f * v;
                C[(size_t)gm * ldc + gn] = (OutT)v;
            }
        }
    }
}

// ---------------------------------------------------------------------------
// MFMA head (used once, for x0): writes softmax/sigmoid into xt0[4096][16].
// ---------------------------------------------------------------------------
__global__ __launch_bounds__(256) void head_mfma(
    const bf16* __restrict__ A, int lda,
    const bf16* __restrict__ Wp16,
    const float* __restrict__ bias,
    bf16* __restrict__ xt_dst, int ldx)
{
    const int t = threadIdx.x;
    const int lane = t & 63, w = t >> 6;
    const int quad = lane >> 4, l16 = lane & 15;
    const int r0 = blockIdx.x * 64 + w * 16;
    f32x4 acc = {};
    for (int kk = 0; kk < 16; ++kk) {
        bf16x8 a = *(const bf16x8*)(A + (size_t)(r0 + l16) * lda + kk * 32 + quad * 8);
        bf16x8 b = *(const bf16x8*)(Wp16 + (size_t)l16 * 512 + kk * 32 + quad * 8);
        acc = __builtin_amdgcn_mfma_f32_16x16x32_bf16(a, b, acc, 0, 0, 0);
    }
    const int n = l16;
    const float bv = bias[n];
    for (int r = 0; r < 4; ++r) {
        float p = acc[r] + bv;
        float vmax = (n == 15) ? -3.0e38f : p;
        for (int m = 1; m < 16; m <<= 1) vmax = fmaxf(vmax, __shfl_xor(vmax, m));
        float e = (n == 15) ? 0.f : __expf(p - vmax);
        float s = e;
        for (int m = 1; m < 16; m <<= 1) s += __shfl_xor(s, m);
        float res = (n == 15) ? sigm(p) : e / s;
        int gr = r0 + quad * 4 + r;
        xt_dst[(size_t)gr * ldx + n] = (bf16)res;
    }
}

// ---------------------------------------------------------------------------
// Persistent fused LSTM, no cache invalidation anywhere.
// 256 blocks (152 KB LDS => exactly 1/CU => all resident by construction).
// Block (mb=bid>>3, jb=bid&7): rows mb*128..+127, units jb*64..+63, 4 gates.
// Only h crosses blocks: writers flush via RELEASE atomic (buffer_wbl2 -
// write-BACK, L2 keeps Wc hot); readers stage A with sc0|sc1 bypass loads
// (aux=17) straight from the coherence point.  xt is accumulated IN-GEMM
// (p += A_frag @ Wp chunk) from the A stream - no ppart, no 2nd exchange.
// c resident in LDS.  K=544: 8 phases of 64 (dbuf) + xt chunk from xA/sBx.
// Step 32 = p-only pass emitting ys[31].
// ---------------------------------------------------------------------------
__global__ __launch_bounds__(256, 1) void lstm_rows(
    bf16* __restrict__ hb0, bf16* __restrict__ hb1,   // [4096,512]
    const bf16* __restrict__ Wc,    // [2048,544] row-major
    const bf16* __restrict__ Wp,    // [16,512]
    const float* __restrict__ bih, const float* __restrict__ bhh,
    const float* __restrict__ bp,
    const float* __restrict__ cb,   // [4096,512] fp32 c0
    const bf16* __restrict__ xt0,   // [4096,16] x0-head (prologue)
    float* __restrict__ outp,       // [4096,512] = [B, T*16]
    unsigned* __restrict__ bvars)   // 32 group records, 16 uints apart
{
    __shared__ __attribute__((aligned(16))) bf16 sA[2][2][128][32];  // 32 KB
    __shared__ __attribute__((aligned(16))) bf16 sB[2][2][256][32];  // 64 KB
    __shared__ __attribute__((aligned(16))) bf16 sBx[256 * 32];      // 16 KB
    __shared__ float sC[128 * 64];                                   // 32 KB
    __shared__ __attribute__((aligned(16))) bf16 xA[128 * 32];       // 8 KB
    const int t = threadIdx.x;
    const int lane = t & 63, w = t >> 6;
    const int wm = w >> 1, wn = w & 1;
    const int quad = lane >> 4, l16 = lane & 15;
    const int bid = blockIdx.x;
    const int jb = bid & 7, mb = bid >> 3;
    const int m0 = mb * 128;
    unsigned* grec = bvars + mb * 16;

    // Wc row for B slot s (0..255): col c=s -> gate=(c>>4)&3, unit=(c>>6)*16+(c&15)
    auto wrow = [&](int s) {
        return (((s >> 4) & 3) << 9) + (jb << 6) + (((s >> 6) << 4) | (s & 15));
    };
    auto stageB = [&](int ph, int buf) {   // 2 planes x [256][32], cached
#pragma unroll
        for (int i = 0; i < 8; ++i) {
            int gi = (i << 8) + t;
            int pl = gi >> 10, s = (gi >> 2) & 255, kof = (gi & 3) << 3;
            glds16(Wc + (size_t)wrow(s) * 544 + ph * 64 + pl * 32 + kof,
                   (char*)&sB[buf][0][0][0] + (size_t)gi * 16);
        }
    };
    auto stageA = [&](const bf16* hin, int ph, int buf) {  // bypass L1+L2
#pragma unroll
        for (int i = 0; i < 4; ++i) {
            int gi = (i << 8) + t;
            int pl = gi >> 9, row = (gi >> 2) & 127, kof = (gi & 3) << 3;
            glds16_byp(hin + (size_t)(m0 + row) * 512 + ph * 64 + pl * 32 + kof,
                       (char*)&sA[buf][0][0][0] + (size_t)gi * 16);
        }
    };

    // ---- one-time init ----
#pragma unroll
    for (int i = 0; i < 4; ++i) {          // sBx: Wc cols 512..543 (Wih||0)
        int gi = (i << 8) + t;
        int s = gi >> 2, kof = (gi & 3) << 3;
        glds16(Wc + (size_t)wrow(s) * 544 + 512 + kof,
               (char*)sBx + (size_t)gi * 16);
    }
#pragma unroll
    for (int i = 0; i < 8; ++i) {          // c slice -> LDS
        int f4 = (i << 8) + t;
        int row = f4 >> 4, u4 = f4 & 15;
        ((float4*)sC)[f4] =
            *(const float4*)(cb + (size_t)(m0 + row) * 512 + jb * 64 + u4 * 4);
    }
    if (t < 128) {                          // xA cols 16..31 stay zero forever
        *(bf16x8*)(xA + t * 32 + 16) = (bf16x8){};
        *(bf16x8*)(xA + t * 32 + 24) = (bf16x8){};
    }
    float bs[2][4];
#pragma unroll
    for (int us = 0; us < 2; ++us) {
        int uu = (wn * 2 + us) * 16 + l16;
#pragma unroll
        for (int g = 0; g < 4; ++g)
            bs[us][g] = bih[(g << 9) + jb * 64 + uu] + bhh[(g << 9) + jb * 64 + uu];
    }
    const float bp_l = bp[l16];

#pragma unroll 1
    for (int st = 0; st <= 32; ++st) {
        const bool last = (st == 32);
        const bf16* hin = (st & 1) ? hb1 : hb0;
        bf16* hout = (st & 1) ? hb0 : hb1;

        stageA(hin, 0, 0);
        if (!last) stageB(0, 0);
        if (st == 0 && t < 128) {           // xt0 -> xA (prologue head output)
            *(bf16x8*)(xA + t * 32) = *(const bf16x8*)(xt0 + (size_t)(m0 + t) * 16);
            *(bf16x8*)(xA + t * 32 + 8) =
                *(const bf16x8*)(xt0 + (size_t)(m0 + t) * 16 + 8);
        }
        __syncthreads();

        f32x4 acc[4][8] = {};
        f32x4 pac[4] = {};
        for (int ph = 0; ph < 8; ++ph) {
            const int cur = ph & 1, nxt = cur ^ 1;
            if (ph < 7) { stageA(hin, ph + 1, nxt); if (!last) stageB(ph + 1, nxt); }
#pragma unroll
            for (int ks = 0; ks < 2; ++ks) {
                bf16x8 af[4];
#pragma unroll
                for (int mi = 0; mi < 4; ++mi)
                    af[mi] = *(const bf16x8*)&sA[cur][ks][wm * 64 + mi * 16 + l16][quad * 8];
                if (st > 0 && wn == 0) {    // in-GEMM head: p += A @ Wp^T
                    bf16x8 wpf = *(const bf16x8*)(Wp + (size_t)l16 * 512 +
                                                  (ph * 2 + ks) * 32 + quad * 8);
#pragma unroll
                    for (int mi = 0; mi < 4; ++mi)
                        pac[mi] = __builtin_amdgcn_mfma_f32_16x16x32_bf16(
                            af[mi], wpf, pac[mi], 0, 0, 0);
                }
                if (!last) {
#pragma unroll
                    for (int ni = 0; ni < 8; ++ni) {
                        bf16x8 bfr = *(const bf16x8*)
                            &sB[cur][ks][wn * 128 + ni * 16 + l16][quad * 8];
#pragma unroll
                        for (int mi = 0; mi < 4; ++mi)
                            acc[mi][ni] = __builtin_amdgcn_mfma_f32_16x16x32_bf16(
                                af[mi], bfr, acc[mi][ni], 0, 0, 0);
                    }
                }
            }
            __syncthreads();
        }

        if (st > 0 && wn == 0) {            // softmax head for this wave's rows
#pragma unroll
            for (int mi = 0; mi < 4; ++mi) {
#pragma unroll
                for (int r = 0; r < 4; ++r) {
                    float pv = pac[mi][r] + bp_l;
                    float vmax = (l16 == 15) ? -3.0e38f : pv;
                    for (int m = 1; m < 16; m <<= 1)
                        vmax = fmaxf(vmax, __shfl_xor(vmax, m));
                    float e = (l16 == 15) ? 0.f : __expf(pv - vmax);
                    float s = e;
                    for (int m = 1; m < 16; m <<= 1) s += __shfl_xor(s, m);
                    float res = (l16 == 15) ? sigm(pv) : e / s;
                    int lr = wm * 64 + mi * 16 + quad * 4 + r;
                    if (!last) xA[lr * 32 + l16] = (bf16)res;
                    if (jb == 0)
                        outp[(size_t)(m0 + lr) * 512 + (st - 1) * 16 + l16] = res;
                }
            }
        }
        if (last) break;
        __syncthreads();                    // xA visible to all waves

        {   // xt chunk (K=32: xt||0 vs Wih||0)
            bf16x8 axt[4];
#pragma unroll
            for (int mi = 0; mi < 4; ++mi)
                axt[mi] = *(const bf16x8*)(xA + (wm * 64 + mi * 16 + l16) * 32 + quad * 8);
#pragma unroll
            for (int ni = 0; ni < 8; ++ni) {
                bf16x8 bfr = *(const bf16x8*)(sBx + (wn * 128 + ni * 16 + l16) * 32 + quad * 8);
#pragma unroll
                for (int mi = 0; mi < 4; ++mi)
                    acc[mi][ni] = __builtin_amdgcn_mfma_f32_16x16x32_bf16(
                        axt[mi], bfr, acc[mi][ni], 0, 0, 0);
            }
        }

        // epilogue: gates -> c (LDS, lane-private) -> h store
#pragma unroll
        for (int mi = 0; mi < 4; ++mi) {
#pragma unroll
            for (int us = 0; us < 2; ++us) {
#pragma unroll
                for (int r = 0; r < 4; ++r) {
                    int lr = wm * 64 + mi * 16 + quad * 4 + r;
                    int uu = (wn * 2 + us) * 16 + l16;
                    float i_ = sigm(acc[mi][us * 4 + 0][r] + bs[us][0]);
                    float f_ = sigm(acc[mi][us * 4 + 1][r] + bs[us][1]);
                    float g_ = tanh_f(acc[mi][us * 4 + 2][r] + bs[us][2]);
                    float o_ = sigm(acc[mi][us * 4 + 3][r] + bs[us][3]);
                    float cn = f_ * sC[lr * 64 + uu] + i_ * g_;
                    sC[lr * 64 + uu] = cn;
                    hout[(size_t)(m0 + lr) * 512 + jb * 64 + uu] =
                        (bf16)(o_ * tanh_f(cn));
                }
            }
        }

        __syncthreads();                    // all waves' h-stores in L2
        if (t == 0) {
            unsigned g0 = __hip_atomic_load(grec + 1, __ATOMIC_RELAXED,
                                            __HIP_MEMORY_SCOPE_AGENT);
            unsigned a = __hip_atomic_fetch_add(grec, 1u, __ATOMIC_RELEASE,
                                                __HIP_MEMORY_SCOPE_AGENT);  // wbl2
            if (a == 7u) {
                __hip_atomic_store(grec, 0u, __ATOMIC_RELAXED,
                                   __HIP_MEMORY_SCOPE_AGENT);
                __hip_atomic_fetch_add(grec + 1, 1u, __ATOMIC_RELEASE,
                                       __HIP_MEMORY_SCOPE_AGENT);
            } else {
                while (__hip_atomic_load(grec + 1, __ATOMIC_RELAXED,
                                         __HIP_MEMORY_SCOPE_AGENT) == g0)
                    __builtin_amdgcn_s_sleep(4);
            }
        }
        __syncthreads();
    }
}

// ---------------------------------------------------------------------------
extern "C" void kernel_launch(void* const* d_in, const int* in_sizes, int n_in,
                              void* d_out, int out_size, void* d_ws, size_t ws_size,
                              hipStream_t stream) {
    const float* xf   = (const float*)d_in[0];
    const float* W1f  = (const float*)d_in[1];  const float* b1  = (const float*)d_in[2];
    const float* W2f  = (const float*)d_in[3];  const float* b2  = (const float*)d_in[4];
    const float* W3f  = (const float*)d_in[5];  const float* b3  = (const float*)d_in[6];
    const float* Wh1f = (const float*)d_in[7];  const float* bh1 = (const float*)d_in[8];
    const float* Wh2f = (const float*)d_in[9];  const float* bh2 = (const float*)d_in[10];
    const float* Wc1f = (const float*)d_in[11]; const float* bc1 = (const float*)d_in[12];
    const float* Wc2f = (const float*)d_in[13]; const float* bc2 = (const float*)d_in[14];
    const float* Wx1f = (const float*)d_in[15]; const float* bx1 = (const float*)d_in[16];
    const float* Wx2f = (const float*)d_in[17]; const float* bx2 = (const float*)d_in[18];
    const float* Wihf = (const float*)d_in[19]; const float* bih = (const float*)d_in[20];
    const float* Whhf = (const float*)d_in[21]; const float* bhh = (const float*)d_in[22];
    const float* Wpf  = (const float*)d_in[23]; const float* bp  = (const float*)d_in[24];
    float* out = (float*)d_out;
    char* ws = (char*)d_ws;

    // layout (bytes): hb1/bufA 0..4456448 | bufB ..8650752 | hb0 ..13107200 |
    // cb ..21495808 | Wcb ..23724032 | cvt ..28606464 | bvars ..28608512
    bf16*  hb1  = (bf16*)(ws + 0);            // loop h odd; early: z-buf (ld 512)
    bf16*  bufA = hb1;
    bf16*  bufB = (bf16*)(ws + 4456448);
    bf16*  hb0  = (bf16*)(ws + 8650752);      // [4096,512]
    float* cb   = (float*)(ws + 13107200);    // [4096,512] fp32
    bf16*  Wcb  = (bf16*)(ws + 21495808);     // [2048,544]
    bf16*  cvt  = (bf16*)(ws + 23724032);     // packed bf16 weights
    unsigned* bvars = (unsigned*)(ws + 28606464);

    const unsigned Ns[11] = {
        4096u * 128u,  // x
        512u * 128u,   // W1
        512u * 512u, 512u * 512u, 512u * 512u, 512u * 512u,  // W2,W3,Wh1,Wh2
        512u * 512u, 512u * 512u, 512u * 512u,               // Wc1,Wc2,Wx1
        16u * 512u,    // Wx2
        16u * 512u     // Wp
    };
    const float* srcs[11] = { xf, W1f, W2f, W3f, Wh1f, Wh2f, Wc1f, Wc2f,
                              Wx1f, Wx2f, Wpf };
    Cvt11 ca;
    unsigned off[12]; off[0] = 0;
    for (int i = 0; i < 11; ++i) {
        ca.src[i] = srcs[i];
        ca.gcnt[i] = Ns[i] >> 3;
        off[i + 1] = off[i] + Ns[i];
    }
    unsigned total_g = off[11] >> 3;
    cvt_all<<<dim3((total_g + 255) / 256), dim3(256), 0, stream>>>(ca, cvt, total_g);
    pack_w<<<dim3(2048), dim3(128), 0, stream>>>(Whhf, Wihf, Wcb);

    const bf16* xb   = cvt + off[0];
    const bf16* W1b  = cvt + off[1];
    const bf16* W2b  = cvt + off[2];
    const bf16* W3b  = cvt + off[3];
    const bf16* Wh1b = cvt + off[4];
    const bf16* Wh2b = cvt + off[5];
    const bf16* Wc1b = cvt + off[6];
    const bf16* Wc2b = cvt + off[7];
    const bf16* Wx1b = cvt + off[8];
    const bf16* Wx2b = cvt + off[9];
    const bf16* Wpb  = cvt + off[10];
    // xt0 aliases the dead x slot (x only used by the first GEMM)
    bf16* xt0 = cvt + off[0];

    dim3 blk(256);
    dim3 gg(4, 64);  // N/128 x M/64
    gemm_bt<1, bf16 ><<<gg, blk, 0, stream>>>(xb,   W1b,  b1,  bufA, 4096, 512, 128, 512);
    gemm_bt<1, bf16 ><<<gg, blk, 0, stream>>>(bufA, W2b,  b2,  bufB, 4096, 512, 512, 512);
    gemm_bt<1, bf16 ><<<gg, blk, 0, stream>>>(bufB, W3b,  b3,  bufA, 4096, 512, 512, 512);
    gemm_bt<1, bf16 ><<<gg, blk, 0, stream>>>(bufA, Wh1b, bh1, bufB, 4096, 512, 512, 512);
    gemm_bt<0, bf16 ><<<gg, blk, 0, stream>>>(bufB, Wh2b, bh2, hb0,  4096, 512, 512, 512);
    gemm_bt<1, bf16 ><<<gg, blk, 0, stream>>>(bufA, Wc1b, bc1, bufB, 4096, 512, 512, 512);
    gemm_bt<0, float><<<gg, blk, 0, stream>>>(bufB, Wc2b, bc2, cb,   4096, 512, 512, 512);
    gemm_bt<1, bf16 ><<<gg, blk, 0, stream>>>(bufA, Wx1b, bx1, bufB, 4096, 512, 512, 512);
    init_bvars<<<dim3(1), blk, 0, stream>>>(bvars);
    head_mfma<<<dim3(64), blk, 0, stream>>>(bufB, 512, Wx2b, bx2, xt0, 16);

    // one persistent kernel: 32 LSTM steps + 33rd p-only pass for ys[31]
    lstm_rows<<<dim3(256), blk, 0, stream>>>(hb0, hb1, Wcb, Wpb,
                                             bih, bhh, bp, cb, xt0, out, bvars);
}

// Round 7
// 1016.174 us; speedup vs baseline: 2.0116x; 1.5451x over previous
//
#include <hip/hip_runtime.h>
#include <hip/hip_bf16.h>

typedef __bf16 bf16;
typedef bf16 bf16x8 __attribute__((ext_vector_type(8)));
typedef float f32x4 __attribute__((ext_vector_type(4)));

__device__ __forceinline__ void glds16(const void* g, void* l) {
    __builtin_amdgcn_global_load_lds(
        (const __attribute__((address_space(1))) void*)g,
        (__attribute__((address_space(3))) void*)l, 16, 0, 0);
}

__device__ __forceinline__ float sigm(float x) { return 1.0f / (1.0f + __expf(-x)); }
__device__ __forceinline__ float tanh_f(float x) { return 2.0f / (1.0f + __expf(-2.0f * x)) - 1.0f; }

// ---------------------------------------------------------------------------
// fp32 -> bf16 conversion of x + 11 matrices into one packed ws area.
// ---------------------------------------------------------------------------
struct Cvt11 { const float* src[11]; unsigned gcnt[11]; };  // gcnt = elems/8

__global__ __launch_bounds__(256) void cvt_all(Cvt11 a, bf16* __restrict__ dst,
                                               unsigned total_g) {
    unsigned g = blockIdx.x * 256 + threadIdx.x;
    if (g >= total_g) return;
    unsigned s = 0, base = 0;
    while (g >= base + a.gcnt[s]) { base += a.gcnt[s]; ++s; }
    const float* sp = a.src[s] + (size_t)(g - base) * 8;
    float4 v0 = ((const float4*)sp)[0];
    float4 v1 = ((const float4*)sp)[1];
    bf16x8 o;
    o[0] = (bf16)v0.x; o[1] = (bf16)v0.y; o[2] = (bf16)v0.z; o[3] = (bf16)v0.w;
    o[4] = (bf16)v1.x; o[5] = (bf16)v1.y; o[6] = (bf16)v1.z; o[7] = (bf16)v1.w;
    *(bf16x8*)(dst + (size_t)g * 8) = o;
}

// Pack WcP[oct=68][2048][8]: oct o holds k-cols o*8..o*8+7 of
// Wcomb[2048,544] = Whh[2048,512] || Wih[2048,16] || zeros[16], bf16.
// A 16-row x 8-col B-fragment load = 16 x 16B contiguous (256 B / quad).
__global__ __launch_bounds__(128) void pack_w(const float* __restrict__ Whh,
                                              const float* __restrict__ Wih,
                                              bf16* __restrict__ WcP) {
    int row = blockIdx.x, seg = threadIdx.x;
    if (seg >= 68) return;
    bf16x8 o = {};
    if (seg < 64) {
        const float* sp = Whh + (size_t)row * 512 + seg * 8;
        float4 v0 = ((const float4*)sp)[0];
        float4 v1 = ((const float4*)sp)[1];
        o[0]=(bf16)v0.x; o[1]=(bf16)v0.y; o[2]=(bf16)v0.z; o[3]=(bf16)v0.w;
        o[4]=(bf16)v1.x; o[5]=(bf16)v1.y; o[6]=(bf16)v1.z; o[7]=(bf16)v1.w;
    } else if (seg < 66) {
        const float* sp = Wih + (size_t)row * 16 + (seg - 64) * 8;
        float4 v0 = ((const float4*)sp)[0];
        float4 v1 = ((const float4*)sp)[1];
        o[0]=(bf16)v0.x; o[1]=(bf16)v0.y; o[2]=(bf16)v0.z; o[3]=(bf16)v0.w;
        o[4]=(bf16)v1.x; o[5]=(bf16)v1.y; o[6]=(bf16)v1.z; o[7]=(bf16)v1.w;
    }
    *(bf16x8*)(WcP + ((size_t)seg * 2048 + row) * 8) = o;
}

// ---------------------------------------------------------------------------
// GEMM: C[M,N](ldc) = act(A[M,K] @ W[N,K]^T + bias).  (prologue, verified)
// ---------------------------------------------------------------------------
template <int ACT, typename OutT>
__global__ __launch_bounds__(256) void gemm_bt(
    const bf16* __restrict__ A, const bf16* __restrict__ W,
    const float* __restrict__ bias, OutT* __restrict__ C,
    int M, int N, int K, int ldc)
{
    __shared__ __attribute__((aligned(16))) bf16 sA[64 * 32];
    __shared__ __attribute__((aligned(16))) bf16 sB[128 * 32];
    const int t = threadIdx.x;
    const int lane = t & 63, w = t >> 6;
    const int wm = w >> 1, wn = w & 1;
    const int quad = lane >> 4, l16 = lane & 15;
    const int m0 = blockIdx.y * 64, n0 = blockIdx.x * 128;

    f32x4 acc[2][4] = {};
    const int nk = K >> 5;
    for (int kc = 0; kc < nk; ++kc) {
        const int k0 = kc << 5;
        if (kc) __syncthreads();
        {
            int row = t >> 2, kof = (t & 3) << 3;
            glds16(A + (size_t)(m0 + row) * K + k0 + kof, (char*)sA + (w << 10));
        }
        for (int i = 0; i < 2; ++i) {
            int gi = (i << 8) + t;
            int row = gi >> 2, kof = (gi & 3) << 3;
            glds16(W + (size_t)(n0 + row) * K + k0 + kof,
                   (char*)sB + (i << 12) + (w << 10));
        }
        __syncthreads();
        bf16x8 af[2], bfr[4];
        for (int mi = 0; mi < 2; ++mi)
            af[mi] = *(const bf16x8*)(sA + ((wm * 32 + mi * 16 + l16) * 32 + quad * 8));
        for (int ni = 0; ni < 4; ++ni)
            bfr[ni] = *(const bf16x8*)(sB + ((wn * 64 + ni * 16 + l16) * 32 + quad * 8));
        for (int mi = 0; mi < 2; ++mi)
            for (int ni = 0; ni < 4; ++ni)
                acc[mi][ni] = __builtin_amdgcn_mfma_f32_16x16x32_bf16(
                    af[mi], bfr[ni], acc[mi][ni], 0, 0, 0);
    }
    for (int mi = 0; mi < 2; ++mi) {
        for (int ni = 0; ni < 4; ++ni) {
            int gn = n0 + wn * 64 + ni * 16 + l16;
            float bv = bias[gn];
            for (int r = 0; r < 4; ++r) {
                int gm = m0 + wm * 32 + mi * 16 + quad * 4 + r;
                float v = acc[mi][ni][r] + bv;
                if (ACT) v = v >= 0.f ? v : 0.2f * v;
                C[(size_t)gm * ldc + gn] = (OutT)v;
            }
        }
    }
}

// ---------------------------------------------------------------------------
// MFMA head (used once, for x0): writes softmax/sigmoid into xt0[4096][16].
// ---------------------------------------------------------------------------
__global__ __launch_bounds__(256) void head_mfma(
    const bf16* __restrict__ A, int lda,
    const bf16* __restrict__ Wp16,
    const float* __restrict__ bias,
    bf16* __restrict__ xt_dst, int ldx)
{
    const int t = threadIdx.x;
    const int lane = t & 63, w = t >> 6;
    const int quad = lane >> 4, l16 = lane & 15;
    const int r0 = blockIdx.x * 64 + w * 16;
    f32x4 acc = {};
    for (int kk = 0; kk < 16; ++kk) {
        bf16x8 a = *(const bf16x8*)(A + (size_t)(r0 + l16) * lda + kk * 32 + quad * 8);
        bf16x8 b = *(const bf16x8*)(Wp16 + (size_t)l16 * 512 + kk * 32 + quad * 8);
        acc = __builtin_amdgcn_mfma_f32_16x16x32_bf16(a, b, acc, 0, 0, 0);
    }
    const int n = l16;
    const float bv = bias[n];
    for (int r = 0; r < 4; ++r) {
        float p = acc[r] + bv;
        float vmax = (n == 15) ? -3.0e38f : p;
        for (int m = 1; m < 16; m <<= 1) vmax = fmaxf(vmax, __shfl_xor(vmax, m));
        float e = (n == 15) ? 0.f : __expf(p - vmax);
        float s = e;
        for (int m = 1; m < 16; m <<= 1) s += __shfl_xor(s, m);
        float res = (n == 15) ? sigm(p) : e / s;
        int gr = r0 + quad * 4 + r;
        xt_dst[(size_t)gr * ldx + n] = (bf16)res;
    }
}

// ---------------------------------------------------------------------------
// lstm_solo: 256 FULLY INDEPENDENT blocks, each running the whole 32-step
// recurrence for 16 batch rows x ALL 512 units.  No inter-block sync, no
// coherence assumptions, no placement sensitivity.
//   - h||xt in LDS sH[2][16][552] (552-stride: 1104B = 12 mod 32 banks ->
//     <=2-way aliasing on b128 fragment reads, free per m136)
//   - c in LDS sC[16][516] f32 (516-stride breaks quad bank overlap)
//   - B = WcP oct-packed, direct L2->VGPR fragments, reg double-buffered,
//     fully unrolled K (17 chunks incl. xt chunk; xt cols 528.. are zeros)
//   - xt_t computed in-block (wave 0: 16-MFMA pac over h_t + 16-lane softmax)
//     = ys[t-1]; step 32 runs pac only for ys[31]
// Per step: wave0 pac -> barrier -> 8 unit-groups x (17x4 MFMA + epilogue)
//           -> barrier.  L2 B-traffic 2.2 MB/CU/step is the intended bound.
// ---------------------------------------------------------------------------
__global__ __launch_bounds__(256, 1) void lstm_solo(
    const bf16* __restrict__ h0g,   // [4096,512] h0 (prologue GEMM)
    const bf16* __restrict__ xt0,   // [4096,16]  x0-head (prologue)
    const bf16* __restrict__ WcP,   // [68][2048][8] oct-packed
    const bf16* __restrict__ Wp,    // [16,512]
    const float* __restrict__ bih, const float* __restrict__ bhh,
    const float* __restrict__ bp,
    const float* __restrict__ cb,   // [4096,512] fp32 c0
    float* __restrict__ outp)       // [4096,512] = [B, T*16]
{
    __shared__ __attribute__((aligned(16))) bf16 sH[2][16][552];  // 34.5 KB
    __shared__ float sC[16 * 516];                                // 33 KB
    __shared__ float sBias[2048];                                 // 8 KB
    const int t = threadIdx.x;
    const int lane = t & 63, w = t >> 6;
    const int quad = lane >> 4, l16 = lane & 15;
    const int m0 = blockIdx.x * 16;

    // ---- one-time init ----
    for (int i = 0; i < 8; ++i)                       // sBias = bih + bhh
        sBias[i * 256 + t] = bih[i * 256 + t] + bhh[i * 256 + t];
#pragma unroll
    for (int i = 0; i < 8; ++i) {                     // sC <- c0
        int idx = i * 256 + t;                        // 2048 float4 slots
        int row = idx >> 7, c4 = idx & 127;
        *(float4*)&sC[row * 516 + c4 * 4] =
            *(const float4*)(cb + (size_t)(m0 + row) * 512 + c4 * 4);
    }
    for (int i = 0; i < 5; ++i) {                     // sH[0] <- h0 || xt0 || 0
        int idx = i * 256 + t;                        // 16 rows x 68 col8
        if (idx < 1088) {
            int row = idx / 68, c8 = idx % 68, col = c8 * 8;
            bf16x8 v = {};
            if (col < 512)
                v = *(const bf16x8*)(h0g + (size_t)(m0 + row) * 512 + col);
            else if (col < 528)
                v = *(const bf16x8*)(xt0 + (size_t)(m0 + row) * 16 + (col - 512));
            *(bf16x8*)&sH[0][row][col] = v;
            if (col >= 528) *(bf16x8*)&sH[1][row][col] = v;  // zeros
        }
    }

    // lane-constant pieces
    const bf16* bb = WcP + (size_t)quad * 16384 + (size_t)(w * 16 + l16) * 8;
    const int uw = w * 16 + l16;                      // unit offset within group
    const float bp_l = bp[l16];
    __syncthreads();

#pragma unroll 1
    for (int st = 0; st <= 32; ++st) {
        const int hc = st & 1, hn = hc ^ 1;

        // ---- phase A (wave 0): xt_st = head(h_st @ Wp^T) = ys[st-1] ----
        if (st > 0 && w == 0) {
            f32x4 pac = {};
#pragma unroll
            for (int kc = 0; kc < 16; ++kc) {
                bf16x8 af = *(const bf16x8*)&sH[hc][l16][kc * 32 + quad * 8];
                bf16x8 wpf = *(const bf16x8*)(Wp + (size_t)l16 * 512 +
                                              kc * 32 + quad * 8);
                pac = __builtin_amdgcn_mfma_f32_16x16x32_bf16(af, wpf, pac, 0, 0, 0);
            }
#pragma unroll
            for (int r = 0; r < 4; ++r) {
                float pv = pac[r] + bp_l;
                float vmax = (l16 == 15) ? -3.0e38f : pv;
                for (int m = 1; m < 16; m <<= 1)
                    vmax = fmaxf(vmax, __shfl_xor(vmax, m));
                float e = (l16 == 15) ? 0.f : __expf(pv - vmax);
                float s = e;
                for (int m = 1; m < 16; m <<= 1) s += __shfl_xor(s, m);
                float res = (l16 == 15) ? sigm(pv) : e / s;
                int row = quad * 4 + r;
                if (st != 32) sH[hc][row][512 + l16] = (bf16)res;
                outp[(size_t)(m0 + row) * 512 + (st - 1) * 16 + l16] = res;
            }
        }
        __syncthreads();
        if (st == 32) break;

        // ---- main GEMM: 8 unit-groups of 64 (x4 gates), K = 17 chunks ----
#pragma unroll 1
        for (int nt = 0; nt < 8; ++nt) {
            const bf16* bnt = bb + (size_t)nt * 512;
            f32x4 acc[4] = {};
            bf16x8 bfr[2][4];
#pragma unroll
            for (int ni = 0; ni < 4; ++ni)            // prime kc=0
                bfr[0][ni] = *(const bf16x8*)(bnt + (size_t)ni * 4096);
#pragma unroll
            for (int kc = 0; kc < 17; ++kc) {
                const int cur = kc & 1;
                if (kc < 16) {
#pragma unroll
                    for (int ni = 0; ni < 4; ++ni)
                        bfr[cur ^ 1][ni] = *(const bf16x8*)
                            (bnt + (size_t)ni * 4096 + (size_t)(kc + 1) * 65536);
                }
                bf16x8 af = *(const bf16x8*)&sH[hc][l16][kc * 32 + quad * 8];
#pragma unroll
                for (int ni = 0; ni < 4; ++ni)
                    acc[ni] = __builtin_amdgcn_mfma_f32_16x16x32_bf16(
                        af, bfr[cur][ni], acc[ni], 0, 0, 0);
            }
            // epilogue for these 64 units: gates -> c (LDS) -> h (LDS)
            const int u = nt * 64 + uw;
#pragma unroll
            for (int r = 0; r < 4; ++r) {
                int row = quad * 4 + r;
                float i_ = sigm(acc[0][r] + sBias[u]);
                float f_ = sigm(acc[1][r] + sBias[512 + u]);
                float g_ = tanh_f(acc[2][r] + sBias[1024 + u]);
                float o_ = sigm(acc[3][r] + sBias[1536 + u]);
                int ci = row * 516 + u;
                float cn = f_ * sC[ci] + i_ * g_;
                sC[ci] = cn;
                sH[hn][row][u] = (bf16)(o_ * tanh_f(cn));
            }
        }
        __syncthreads();   // h_{st+1} complete; sH[hc] reads all done
    }
}

// ---------------------------------------------------------------------------
extern "C" void kernel_launch(void* const* d_in, const int* in_sizes, int n_in,
                              void* d_out, int out_size, void* d_ws, size_t ws_size,
                              hipStream_t stream) {
    const float* xf   = (const float*)d_in[0];
    const float* W1f  = (const float*)d_in[1];  const float* b1  = (const float*)d_in[2];
    const float* W2f  = (const float*)d_in[3];  const float* b2  = (const float*)d_in[4];
    const float* W3f  = (const float*)d_in[5];  const float* b3  = (const float*)d_in[6];
    const float* Wh1f = (const float*)d_in[7];  const float* bh1 = (const float*)d_in[8];
    const float* Wh2f = (const float*)d_in[9];  const float* bh2 = (const float*)d_in[10];
    const float* Wc1f = (const float*)d_in[11]; const float* bc1 = (const float*)d_in[12];
    const float* Wc2f = (const float*)d_in[13]; const float* bc2 = (const float*)d_in[14];
    const float* Wx1f = (const float*)d_in[15]; const float* bx1 = (const float*)d_in[16];
    const float* Wx2f = (const float*)d_in[17]; const float* bx2 = (const float*)d_in[18];
    const float* Wihf = (const float*)d_in[19]; const float* bih = (const float*)d_in[20];
    const float* Whhf = (const float*)d_in[21]; const float* bhh = (const float*)d_in[22];
    const float* Wpf  = (const float*)d_in[23]; const float* bp  = (const float*)d_in[24];
    float* out = (float*)d_out;
    char* ws = (char*)d_ws;

    // layout (bytes): bufA 0..4456448 | bufB ..8650752 | hb0 ..13107200 |
    // cb ..21495808 | WcP ..23724032 | cvt ..28606464
    bf16*  bufA = (bf16*)(ws + 0);
    bf16*  bufB = (bf16*)(ws + 4456448);
    bf16*  hb0  = (bf16*)(ws + 8650752);      // [4096,512]
    float* cb   = (float*)(ws + 13107200);    // [4096,512] fp32
    bf16*  WcP  = (bf16*)(ws + 21495808);     // [68][2048][8]
    bf16*  cvt  = (bf16*)(ws + 23724032);     // packed bf16 weights

    const unsigned Ns[11] = {
        4096u * 128u,  // x
        512u * 128u,   // W1
        512u * 512u, 512u * 512u, 512u * 512u, 512u * 512u,  // W2,W3,Wh1,Wh2
        512u * 512u, 512u * 512u, 512u * 512u,               // Wc1,Wc2,Wx1
        16u * 512u,    // Wx2
        16u * 512u     // Wp
    };
    const float* srcs[11] = { xf, W1f, W2f, W3f, Wh1f, Wh2f, Wc1f, Wc2f,
                              Wx1f, Wx2f, Wpf };
    Cvt11 ca;
    unsigned off[12]; off[0] = 0;
    for (int i = 0; i < 11; ++i) {
        ca.src[i] = srcs[i];
        ca.gcnt[i] = Ns[i] >> 3;
        off[i + 1] = off[i] + Ns[i];
    }
    unsigned total_g = off[11] >> 3;
    cvt_all<<<dim3((total_g + 255) / 256), dim3(256), 0, stream>>>(ca, cvt, total_g);
    pack_w<<<dim3(2048), dim3(128), 0, stream>>>(Whhf, Wihf, WcP);

    const bf16* xb   = cvt + off[0];
    const bf16* W1b  = cvt + off[1];
    const bf16* W2b  = cvt + off[2];
    const bf16* W3b  = cvt + off[3];
    const bf16* Wh1b = cvt + off[4];
    const bf16* Wh2b = cvt + off[5];
    const bf16* Wc1b = cvt + off[6];
    const bf16* Wc2b = cvt + off[7];
    const bf16* Wx1b = cvt + off[8];
    const bf16* Wx2b = cvt + off[9];
    const bf16* Wpb  = cvt + off[10];
    // xt0 aliases the dead x slot (x only used by the first GEMM)
    bf16* xt0 = cvt + off[0];

    dim3 blk(256);
    dim3 gg(4, 64);  // N/128 x M/64
    gemm_bt<1, bf16 ><<<gg, blk, 0, stream>>>(xb,   W1b,  b1,  bufA, 4096, 512, 128, 512);
    gemm_bt<1, bf16 ><<<gg, blk, 0, stream>>>(bufA, W2b,  b2,  bufB, 4096, 512, 512, 512);
    gemm_bt<1, bf16 ><<<gg, blk, 0, stream>>>(bufB, W3b,  b3,  bufA, 4096, 512, 512, 512);
    gemm_bt<1, bf16 ><<<gg, blk, 0, stream>>>(bufA, Wh1b, bh1, bufB, 4096, 512, 512, 512);
    gemm_bt<0, bf16 ><<<gg, blk, 0, stream>>>(bufB, Wh2b, bh2, hb0,  4096, 512, 512, 512);
    gemm_bt<1, bf16 ><<<gg, blk, 0, stream>>>(bufA, Wc1b, bc1, bufB, 4096, 512, 512, 512);
    gemm_bt<0, float><<<gg, blk, 0, stream>>>(bufB, Wc2b, bc2, cb,   4096, 512, 512, 512);
    gemm_bt<1, bf16 ><<<gg, blk, 0, stream>>>(bufA, Wx1b, bx1, bufB, 4096, 512, 512, 512);
    head_mfma<<<dim3(64), blk, 0, stream>>>(bufB, 512, Wx2b, bx2, xt0, 16);

    // 256 independent per-CU recurrences; no inter-block communication
    lstm_solo<<<dim3(256), blk, 0, stream>>>(hb0, xt0, WcP, Wpb,
                                             bih, bhh, bp, cb, out);
}

// Round 9
// 984.800 us; speedup vs baseline: 2.0757x; 1.0319x over previous
//
#include <hip/hip_runtime.h>
#include <hip/hip_bf16.h>

typedef __bf16 bf16;
typedef bf16 bf16x8 __attribute__((ext_vector_type(8)));
typedef float f32x4 __attribute__((ext_vector_type(4)));

__device__ __forceinline__ void glds16(const void* g, void* l) {
    __builtin_amdgcn_global_load_lds(
        (const __attribute__((address_space(1))) void*)g,
        (__attribute__((address_space(3))) void*)l, 16, 0, 0);
}

__device__ __forceinline__ float sigm(float x) { return 1.0f / (1.0f + __expf(-x)); }
__device__ __forceinline__ float tanh_f(float x) { return 2.0f / (1.0f + __expf(-2.0f * x)) - 1.0f; }

// ---------------------------------------------------------------------------
// fp32 -> bf16 conversion of x + 11 matrices into one packed ws area.
// ---------------------------------------------------------------------------
struct Cvt11 { const float* src[11]; unsigned gcnt[11]; };  // gcnt = elems/8

__global__ __launch_bounds__(256) void cvt_all(Cvt11 a, bf16* __restrict__ dst,
                                               unsigned total_g) {
    unsigned g = blockIdx.x * 256 + threadIdx.x;
    if (g >= total_g) return;
    unsigned s = 0, base = 0;
    while (g >= base + a.gcnt[s]) { base += a.gcnt[s]; ++s; }
    const float* sp = a.src[s] + (size_t)(g - base) * 8;
    float4 v0 = ((const float4*)sp)[0];
    float4 v1 = ((const float4*)sp)[1];
    bf16x8 o;
    o[0] = (bf16)v0.x; o[1] = (bf16)v0.y; o[2] = (bf16)v0.z; o[3] = (bf16)v0.w;
    o[4] = (bf16)v1.x; o[5] = (bf16)v1.y; o[6] = (bf16)v1.z; o[7] = (bf16)v1.w;
    *(bf16x8*)(dst + (size_t)g * 8) = o;
}

// Pack WcP[oct=68][2048][8]: oct o holds k-cols o*8..o*8+7 of
// Wcomb[2048,544] = Whh[2048,512] || Wih[2048,16] || zeros[16], bf16.
__global__ __launch_bounds__(128) void pack_w(const float* __restrict__ Whh,
                                              const float* __restrict__ Wih,
                                              bf16* __restrict__ WcP) {
    int row = blockIdx.x, seg = threadIdx.x;
    if (seg >= 68) return;
    bf16x8 o = {};
    if (seg < 64) {
        const float* sp = Whh + (size_t)row * 512 + seg * 8;
        float4 v0 = ((const float4*)sp)[0];
        float4 v1 = ((const float4*)sp)[1];
        o[0]=(bf16)v0.x; o[1]=(bf16)v0.y; o[2]=(bf16)v0.z; o[3]=(bf16)v0.w;
        o[4]=(bf16)v1.x; o[5]=(bf16)v1.y; o[6]=(bf16)v1.z; o[7]=(bf16)v1.w;
    } else if (seg < 66) {
        const float* sp = Wih + (size_t)row * 16 + (seg - 64) * 8;
        float4 v0 = ((const float4*)sp)[0];
        float4 v1 = ((const float4*)sp)[1];
        o[0]=(bf16)v0.x; o[1]=(bf16)v0.y; o[2]=(bf16)v0.z; o[3]=(bf16)v0.w;
        o[4]=(bf16)v1.x; o[5]=(bf16)v1.y; o[6]=(bf16)v1.z; o[7]=(bf16)v1.w;
    }
    *(bf16x8*)(WcP + ((size_t)seg * 2048 + row) * 8) = o;
}

// ---------------------------------------------------------------------------
// GEMM: C[M,N](ldc) = act(A[M,K] @ W[N,K]^T + bias).  (prologue, verified)
// ---------------------------------------------------------------------------
template <int ACT, typename OutT>
__global__ __launch_bounds__(256) void gemm_bt(
    const bf16* __restrict__ A, const bf16* __restrict__ W,
    const float* __restrict__ bias, OutT* __restrict__ C,
    int M, int N, int K, int ldc)
{
    __shared__ __attribute__((aligned(16))) bf16 sA[64 * 32];
    __shared__ __attribute__((aligned(16))) bf16 sB[128 * 32];
    const int t = threadIdx.x;
    const int lane = t & 63, w = t >> 6;
    const int wm = w >> 1, wn = w & 1;
    const int quad = lane >> 4, l16 = lane & 15;
    const int m0 = blockIdx.y * 64, n0 = blockIdx.x * 128;

    f32x4 acc[2][4] = {};
    const int nk = K >> 5;
    for (int kc = 0; kc < nk; ++kc) {
        const int k0 = kc << 5;
        if (kc) __syncthreads();
        {
            int row = t >> 2, kof = (t & 3) << 3;
            glds16(A + (size_t)(m0 + row) * K + k0 + kof, (char*)sA + (w << 10));
        }
        for (int i = 0; i < 2; ++i) {
            int gi = (i << 8) + t;
            int row = gi >> 2, kof = (gi & 3) << 3;
            glds16(W + (size_t)(n0 + row) * K + k0 + kof,
                   (char*)sB + (i << 12) + (w << 10));
        }
        __syncthreads();
        bf16x8 af[2], bfr[4];
        for (int mi = 0; mi < 2; ++mi)
            af[mi] = *(const bf16x8*)(sA + ((wm * 32 + mi * 16 + l16) * 32 + quad * 8));
        for (int ni = 0; ni < 4; ++ni)
            bfr[ni] = *(const bf16x8*)(sB + ((wn * 64 + ni * 16 + l16) * 32 + quad * 8));
        for (int mi = 0; mi < 2; ++mi)
            for (int ni = 0; ni < 4; ++ni)
                acc[mi][ni] = __builtin_amdgcn_mfma_f32_16x16x32_bf16(
                    af[mi], bfr[ni], acc[mi][ni], 0, 0, 0);
    }
    for (int mi = 0; mi < 2; ++mi) {
        for (int ni = 0; ni < 4; ++ni) {
            int gn = n0 + wn * 64 + ni * 16 + l16;
            float bv = bias[gn];
            for (int r = 0; r < 4; ++r) {
                int gm = m0 + wm * 32 + mi * 16 + quad * 4 + r;
                float v = acc[mi][ni][r] + bv;
                if (ACT) v = v >= 0.f ? v : 0.2f * v;
                C[(size_t)gm * ldc + gn] = (OutT)v;
            }
        }
    }
}

// ---------------------------------------------------------------------------
// MFMA head (used once, for x0): writes softmax/sigmoid into xt0[4096][16].
// ---------------------------------------------------------------------------
__global__ __launch_bounds__(256) void head_mfma(
    const bf16* __restrict__ A, int lda,
    const bf16* __restrict__ Wp16,
    const float* __restrict__ bias,
    bf16* __restrict__ xt_dst, int ldx)
{
    const int t = threadIdx.x;
    const int lane = t & 63, w = t >> 6;
    const int quad = lane >> 4, l16 = lane & 15;
    const int r0 = blockIdx.x * 64 + w * 16;
    f32x4 acc = {};
    for (int kk = 0; kk < 16; ++kk) {
        bf16x8 a = *(const bf16x8*)(A + (size_t)(r0 + l16) * lda + kk * 32 + quad * 8);
        bf16x8 b = *(const bf16x8*)(Wp16 + (size_t)l16 * 512 + kk * 32 + quad * 8);
        acc = __builtin_amdgcn_mfma_f32_16x16x32_bf16(a, b, acc, 0, 0, 0);
    }
    const int n = l16;
    const float bv = bias[n];
    for (int r = 0; r < 4; ++r) {
        float p = acc[r] + bv;
        float vmax = (n == 15) ? -3.0e38f : p;
        for (int m = 1; m < 16; m <<= 1) vmax = fmaxf(vmax, __shfl_xor(vmax, m));
        float e = (n == 15) ? 0.f : __expf(p - vmax);
        float s = e;
        for (int m = 1; m < 16; m <<= 1) s += __shfl_xor(s, m);
        float res = (n == 15) ? sigm(p) : e / s;
        int gr = r0 + quad * 4 + r;
        xt_dst[(size_t)gr * ldx + n] = (bf16)res;
    }
}

// ---------------------------------------------------------------------------
// lstm_solo32: 128 independent blocks x 32 rows x all 512 units, 512 threads
// (8 waves = 2/SIMD).  Each B fragment feeds TWO 16-row tiles (af[2], 8 MFMA
// per kc) -> total L2 B-traffic halves vs R7 (36 MB/XCD/step, ~8 us floor);
// 2 waves/SIMD + depth-2 register prefetch cover L2 latency.
//   - h||xt in LDS sH[2][32][552]; c in sC[32][516] f32; biases in LDS
//   - B direct L2->VGPR from oct-packed WcP, 3 rotating buffers
//   - head in-block: waves 0/1 (one per row-tile) compute xt_t = ys[t-1]
// No inter-block communication of any kind.
// ---------------------------------------------------------------------------
__global__ __launch_bounds__(512, 1) void lstm_solo32(
    const bf16* __restrict__ h0g,   // [4096,512] h0 (prologue GEMM)
    const bf16* __restrict__ xt0,   // [4096,16]  x0-head (prologue)
    const bf16* __restrict__ WcP,   // [68][2048][8] oct-packed
    const bf16* __restrict__ Wp,    // [16,512]
    const float* __restrict__ bih, const float* __restrict__ bhh,
    const float* __restrict__ bp,
    const float* __restrict__ cb,   // [4096,512] fp32 c0
    float* __restrict__ outp)       // [4096,512] = [B, T*16]
{
    __shared__ __attribute__((aligned(16))) bf16 sH[2][32][552];  // 69 KB
    __shared__ float sC[32 * 516];                                // 64.5 KB
    __shared__ float sBias[2048];                                 // 8 KB
    const int t = threadIdx.x;
    const int lane = t & 63, w = t >> 6;         // 8 waves
    const int quad = lane >> 4, l16 = lane & 15;
    const int m0 = blockIdx.x * 32;

    // ---- one-time init ----
    for (int i = 0; i < 4; ++i)                       // sBias = bih + bhh
        sBias[i * 512 + t] = bih[i * 512 + t] + bhh[i * 512 + t];
#pragma unroll
    for (int i = 0; i < 8; ++i) {                     // sC <- c0 (32x512 f32)
        int idx = i * 512 + t;                        // 4096 float4 slots
        int row = idx >> 7, c4 = idx & 127;
        *(float4*)&sC[row * 516 + c4 * 4] =
            *(const float4*)(cb + (size_t)(m0 + row) * 512 + c4 * 4);
    }
    for (int i = 0; i < 5; ++i) {                     // sH[0] <- h0 || xt0 || 0
        int idx = i * 512 + t;                        // 32 rows x 68 col8
        if (idx < 2176) {
            int row = idx / 68, c8 = idx % 68, col = c8 * 8;
            bf16x8 v = {};
            if (col < 512)
                v = *(const bf16x8*)(h0g + (size_t)(m0 + row) * 512 + col);
            else if (col < 528)
                v = *(const bf16x8*)(xt0 + (size_t)(m0 + row) * 16 + (col - 512));
            *(bf16x8*)&sH[0][row][col] = v;
            if (col >= 528) *(bf16x8*)&sH[1][row][col] = v;  // zeros forever
        }
    }

    // lane-constant pieces: wave w owns units uw = w*16+l16 of each 128-group
    const int uw = w * 16 + l16;
    const bf16* bb = WcP + (size_t)quad * 16384 + (size_t)uw * 8;
    const float bp_l = bp[l16];
    __syncthreads();

#pragma unroll 1
    for (int st = 0; st <= 32; ++st) {
        const int hc = st & 1, hn = hc ^ 1;

        // ---- phase A (waves 0,1): xt_st = head(h_st @ Wp^T) = ys[st-1] ----
        if (st > 0 && w < 2) {
            f32x4 pac = {};
#pragma unroll
            for (int kc = 0; kc < 16; ++kc) {
                bf16x8 af = *(const bf16x8*)&sH[hc][w * 16 + l16][kc * 32 + quad * 8];
                bf16x8 wpf = *(const bf16x8*)(Wp + (size_t)l16 * 512 +
                                              kc * 32 + quad * 8);
                pac = __builtin_amdgcn_mfma_f32_16x16x32_bf16(af, wpf, pac, 0, 0, 0);
            }
#pragma unroll
            for (int r = 0; r < 4; ++r) {
                float pv = pac[r] + bp_l;
                float vmax = (l16 == 15) ? -3.0e38f : pv;
                for (int m = 1; m < 16; m <<= 1)
                    vmax = fmaxf(vmax, __shfl_xor(vmax, m));
                float e = (l16 == 15) ? 0.f : __expf(pv - vmax);
                float s = e;
                for (int m = 1; m < 16; m <<= 1) s += __shfl_xor(s, m);
                float res = (l16 == 15) ? sigm(pv) : e / s;
                int row = w * 16 + quad * 4 + r;
                if (st != 32) sH[hc][row][512 + l16] = (bf16)res;
                outp[(size_t)(m0 + row) * 512 + (st - 1) * 16 + l16] = res;
            }
        }
        __syncthreads();
        if (st == 32) break;

        // ---- main GEMM: 4 groups of 128 units (x4 gates), K = 17 chunks ----
#pragma unroll 1
        for (int nt = 0; nt < 4; ++nt) {
            const bf16* bnt = bb + (size_t)nt * 1024;   // +128 units
            f32x4 acc[2][4] = {};                        // [row-tile][gate]
            bf16x8 bfr[3][4];                            // depth-2 prefetch
#pragma unroll
            for (int ni = 0; ni < 4; ++ni) {
                bfr[0][ni] = *(const bf16x8*)(bnt + (size_t)ni * 4096);
                bfr[1][ni] = *(const bf16x8*)(bnt + (size_t)ni * 4096 + 65536);
            }
#pragma unroll
            for (int kc = 0; kc < 17; ++kc) {
                const int cur = kc % 3;
                if (kc < 15) {
                    const int nx = (kc + 2) % 3;
#pragma unroll
                    for (int ni = 0; ni < 4; ++ni)
                        bfr[nx][ni] = *(const bf16x8*)
                            (bnt + (size_t)ni * 4096 + (size_t)(kc + 2) * 65536);
                }
                bf16x8 af0 = *(const bf16x8*)&sH[hc][l16][kc * 32 + quad * 8];
                bf16x8 af1 = *(const bf16x8*)&sH[hc][16 + l16][kc * 32 + quad * 8];
#pragma unroll
                for (int ni = 0; ni < 4; ++ni) {
                    acc[0][ni] = __builtin_amdgcn_mfma_f32_16x16x32_bf16(
                        af0, bfr[cur][ni], acc[0][ni], 0, 0, 0);
                    acc[1][ni] = __builtin_amdgcn_mfma_f32_16x16x32_bf16(
                        af1, bfr[cur][ni], acc[1][ni], 0, 0, 0);
                }
            }
            // epilogue for these 128 units: gates -> c (LDS) -> h (LDS)
            const int u = nt * 128 + uw;
#pragma unroll
            for (int mi = 0; mi < 2; ++mi) {
#pragma unroll
                for (int r = 0; r < 4; ++r) {
                    int row = mi * 16 + quad * 4 + r;
                    float i_ = sigm(acc[mi][0][r] + sBias[u]);
                    float f_ = sigm(acc[mi][1][r] + sBias[512 + u]);
                    float g_ = tanh_f(acc[mi][2][r] + sBias[1024 + u]);
                    float o_ = sigm(acc[mi][3][r] + sBias[1536 + u]);
                    int ci = row * 516 + u;
                    float cn = f_ * sC[ci] + i_ * g_;
                    sC[ci] = cn;
                    sH[hn][row][u] = (bf16)(o_ * tanh_f(cn));
                }
            }
        }
        __syncthreads();   // h_{st+1} complete; all sH[hc] reads done
    }
}

// ---------------------------------------------------------------------------
extern "C" void kernel_launch(void* const* d_in, const int* in_sizes, int n_in,
                              void* d_out, int out_size, void* d_ws, size_t ws_size,
                              hipStream_t stream) {
    const float* xf   = (const float*)d_in[0];
    const float* W1f  = (const float*)d_in[1];  const float* b1  = (const float*)d_in[2];
    const float* W2f  = (const float*)d_in[3];  const float* b2  = (const float*)d_in[4];
    const float* W3f  = (const float*)d_in[5];  const float* b3  = (const float*)d_in[6];
    const float* Wh1f = (const float*)d_in[7];  const float* bh1 = (const float*)d_in[8];
    const float* Wh2f = (const float*)d_in[9];  const float* bh2 = (const float*)d_in[10];
    const float* Wc1f = (const float*)d_in[11]; const float* bc1 = (const float*)d_in[12];
    const float* Wc2f = (const float*)d_in[13]; const float* bc2 = (const float*)d_in[14];
    const float* Wx1f = (const float*)d_in[15]; const float* bx1 = (const float*)d_in[16];
    const float* Wx2f = (const float*)d_in[17]; const float* bx2 = (const float*)d_in[18];
    const float* Wihf = (const float*)d_in[19]; const float* bih = (const float*)d_in[20];
    const float* Whhf = (const float*)d_in[21]; const float* bhh = (const float*)d_in[22];
    const float* Wpf  = (const float*)d_in[23]; const float* bp  = (const float*)d_in[24];
    float* out = (float*)d_out;
    char* ws = (char*)d_ws;

    // layout (bytes): bufA 0..4456448 | bufB ..8650752 | hb0 ..13107200 |
    // cb ..21495808 | WcP ..23724032 | cvt ..28606464
    bf16*  bufA = (bf16*)(ws + 0);
    bf16*  bufB = (bf16*)(ws + 4456448);
    bf16*  hb0  = (bf16*)(ws + 8650752);      // [4096,512]
    float* cb   = (float*)(ws + 13107200);    // [4096,512] fp32
    bf16*  WcP  = (bf16*)(ws + 21495808);     // [68][2048][8]
    bf16*  cvt  = (bf16*)(ws + 23724032);     // packed bf16 weights

    const unsigned Ns[11] = {
        4096u * 128u,  // x
        512u * 128u,   // W1
        512u * 512u, 512u * 512u, 512u * 512u, 512u * 512u,  // W2,W3,Wh1,Wh2
        512u * 512u, 512u * 512u, 512u * 512u,               // Wc1,Wc2,Wx1
        16u * 512u,    // Wx2
        16u * 512u     // Wp
    };
    const float* srcs[11] = { xf, W1f, W2f, W3f, Wh1f, Wh2f, Wc1f, Wc2f,
                              Wx1f, Wx2f, Wpf };
    Cvt11 ca;
    unsigned off[12]; off[0] = 0;
    for (int i = 0; i < 11; ++i) {
        ca.src[i] = srcs[i];
        ca.gcnt[i] = Ns[i] >> 3;
        off[i + 1] = off[i] + Ns[i];
    }
    unsigned total_g = off[11] >> 3;
    cvt_all<<<dim3((total_g + 255) / 256), dim3(256), 0, stream>>>(ca, cvt, total_g);
    pack_w<<<dim3(2048), dim3(128), 0, stream>>>(Whhf, Wihf, WcP);

    const bf16* xb   = cvt + off[0];
    const bf16* W1b  = cvt + off[1];
    const bf16* W2b  = cvt + off[2];
    const bf16* W3b  = cvt + off[3];
    const bf16* Wh1b = cvt + off[4];
    const bf16* Wh2b = cvt + off[5];
    const bf16* Wc1b = cvt + off[6];
    const bf16* Wc2b = cvt + off[7];
    const bf16* Wx1b = cvt + off[8];
    const bf16* Wx2b = cvt + off[9];
    const bf16* Wpb  = cvt + off[10];
    // xt0 aliases the dead x slot (x only used by the first GEMM)
    bf16* xt0 = cvt + off[0];

    dim3 blk(256);
    dim3 gg(4, 64);  // N/128 x M/64
    gemm_bt<1, bf16 ><<<gg, blk, 0, stream>>>(xb,   W1b,  b1,  bufA, 4096, 512, 128, 512);
    gemm_bt<1, bf16 ><<<gg, blk, 0, stream>>>(bufA, W2b,  b2,  bufB, 4096, 512, 512, 512);
    gemm_bt<1, bf16 ><<<gg, blk, 0, stream>>>(bufB, W3b,  b3,  bufA, 4096, 512, 512, 512);
    gemm_bt<1, bf16 ><<<gg, blk, 0, stream>>>(bufA, Wh1b, bh1, bufB, 4096, 512, 512, 512);
    gemm_bt<0, bf16 ><<<gg, blk, 0, stream>>>(bufB, Wh2b, bh2, hb0,  4096, 512, 512, 512);
    gemm_bt<1, bf16 ><<<gg, blk, 0, stream>>>(bufA, Wc1b, bc1, bufB, 4096, 512, 512, 512);
    gemm_bt<0, float><<<gg, blk, 0, stream>>>(bufB, Wc2b, bc2, cb,   4096, 512, 512, 512);
    gemm_bt<1, bf16 ><<<gg, blk, 0, stream>>>(bufA, Wx1b, bx1, bufB, 4096, 512, 512, 512);
    head_mfma<<<dim3(64), blk, 0, stream>>>(bufB, 512, Wx2b, bx2, xt0, 16);

    // 128 independent per-CU recurrences; no inter-block communication
    lstm_solo32<<<dim3(128), dim3(512), 0, stream>>>(hb0, xt0, WcP, Wpb,
                                                     bih, bhh, bp, cb, out);
}